// Round 16
// baseline (168.851 us; speedup 1.0000x reference)
//
#include <hip/hip_runtime.h>

#define N_SEQ 8192
#define HDIM  128

typedef _Float16 half8v  __attribute__((ext_vector_type(8)));
typedef float    floatx16 __attribute__((ext_vector_type(16)));
typedef unsigned int uint32;

// ---------------------------------------------------------------------------
// prep_kv: one block per 32-key tile. Stages K and V fp32 tiles in LDS, then
// writes f16 fragments in EXACT mfma operand order, lane-major. Also zeroes
// the 64 per-y-group merge counters (block 0) -- stream order guarantees
// this lands before fa_main's atomics, replacing a memset dispatch (~11us).
// ---------------------------------------------------------------------------
__global__ void prep_kv(const float* __restrict__ K, const float* __restrict__ V,
                        _Float16* __restrict__ K16s, _Float16* __restrict__ Vs,
                        int* __restrict__ counters) {
    __shared__ float Kl[32 * 132];
    __shared__ float Vl[32 * 132];
    const int t  = threadIdx.x;
    const int nt = blockIdx.x;
    const int n0 = nt * 32;
    if (nt == 0 && t < 64) counters[t] = 0;
    #pragma unroll
    for (int kk = 0; kk < 4; kk++) {
        int idx = t + 256 * kk;
        int nl = idx >> 5, c4 = idx & 31;
        float4 f = *(((const float4*)(K + (size_t)(n0 + nl) * HDIM)) + c4);
        float* dk = &Kl[nl * 132 + c4 * 4];
        dk[0] = f.x; dk[1] = f.y; dk[2] = f.z; dk[3] = f.w;
        float4 g = *(((const float4*)(V + (size_t)(n0 + nl) * HDIM)) + c4);
        float* dv = &Vl[nl * 132 + c4 * 4];
        dv[0] = g.x; dv[1] = g.y; dv[2] = g.z; dv[3] = g.w;
    }
    __syncthreads();
    #pragma unroll
    for (int rep = 0; rep < 2; rep++) {
        int ch = t + rep * 256;
        int kc = ch >> 6, lane = ch & 63, l31 = lane & 31, q5 = (lane >> 5) & 1;
        half8v h;
        #pragma unroll
        for (int j = 0; j < 8; j++) h[j] = (_Float16)Kl[l31 * 132 + kc * 16 + q5 * 8 + j];
        *(half8v*)(K16s + (((size_t)nt * 8 + kc) * 64 + lane) * 8) = h;
    }
    #pragma unroll
    for (int rep = 0; rep < 2; rep++) {
        int ch = t + rep * 256;
        int dt = ch >> 7, kc2 = (ch >> 6) & 1, lane = ch & 63, l31 = lane & 31, q5 = (lane >> 5) & 1;
        half8v h;
        #pragma unroll
        for (int j = 0; j < 8; j++) h[j] = (_Float16)Vl[(kc2 * 16 + q5 * 8 + j) * 132 + dt * 32 + l31];
        *(half8v*)(Vs + ((((size_t)nt * 4 + dt) * 2 + kc2) * 64 + lane) * 8) = h;
    }
}

// ---------------------------------------------------------------------------
// stage_tile: async global->LDS copy of one 32-key tile (K 8KB + V 8KB) into
// a 16KB LDS region, 4 chunks/wave. Layouts are lane-major 1KB chunks, so the
// wave-uniform-base + lane*16 LDS write pattern of global_load_lds matches.
// Completion fenced by the caller's __syncthreads (vmcnt(0) before s_barrier).
// ---------------------------------------------------------------------------
static __device__ __forceinline__ void stage_tile(
        const _Float16* __restrict__ K16s, const _Float16* __restrict__ Vs,
        _Float16* lds, size_t nt, int wv, int lane) {
    #pragma unroll
    for (int i = 0; i < 4; i++) {
        const int c = wv * 4 + i;
        const _Float16* base = (c < 8) ? (K16s + (nt * 8 + c) * 512)
                                       : (Vs + (nt * 8 + (size_t)(c - 8)) * 512);
        __builtin_amdgcn_global_load_lds(
            (const __attribute__((address_space(1))) void*)(base + lane * 8),
            (__attribute__((address_space(3))) void*)(lds + c * 512),
            16, 0, 0);
    }
}

// ---- PV: oacc += V(tile) . P(tile), P given as packed-f16 C-layout regs ----
static __device__ __forceinline__ void do_pv(const half8v (&vsrc)[8], const uint32 (&hpk)[8],
                                             floatx16 (&oacc)[4], int q5) {
    #pragma unroll
    for (int kc2 = 0; kc2 < 2; kc2++) {
        uint32 pass0 = q5 ? hpk[4 * kc2 + 0] : hpk[4 * kc2 + 2];
        uint32 pass1 = q5 ? hpk[4 * kc2 + 1] : hpk[4 * kc2 + 3];
        uint32 r0 = (uint32)__shfl_xor((int)pass0, 32, 64);
        uint32 r1 = (uint32)__shfl_xor((int)pass1, 32, 64);
        uint32 b0 = q5 ? r0 : hpk[4 * kc2 + 0];
        uint32 b1 = q5 ? r1 : hpk[4 * kc2 + 1];
        uint32 b2 = q5 ? hpk[4 * kc2 + 2] : r0;
        uint32 b3 = q5 ? hpk[4 * kc2 + 3] : r1;
        uint4 bu = make_uint4(b0, b1, b2, b3);
        half8v bfrag = __builtin_bit_cast(half8v, bu);
        #pragma unroll
        for (int dt = 0; dt < 4; dt++)
            oacc[dt] = __builtin_amdgcn_mfma_f32_32x32x16_f16(vsrc[dt * 2 + kc2], bfrag, oacc[dt], 0, 0, 0);
    }
}

// ---------------------------------------------------------------------------
// step64: one BN=64 phase (two 32-key sub-tiles A,B from one 32KB buffer).
// In-phase PV: V is ds_read AFTER softmax from the SAME buffer (stage writes
// go to the other buffer -> no cross-phase V registers, no race).
// Buffer layout: [K_A 8K][V_A 8K][K_B 8K][V_B 8K].
// ---------------------------------------------------------------------------
static __device__ __forceinline__ void step64(
        const half8v (&qf)[8], floatx16 (&oacc)[4],
        float& runm, float& lsum,
        const _Float16* lds, int lane, int q5) {
    // ---- S_A = K_A . Q^T ----
    half8v kf[8];
    #pragma unroll
    for (int kc = 0; kc < 8; kc++)
        kf[kc] = *(const half8v*)(lds + kc * 512 + lane * 8);
    floatx16 s0, s1;
    #pragma unroll
    for (int r = 0; r < 16; r++) { s0[r] = 0.0f; s1[r] = 0.0f; }
    #pragma unroll
    for (int kc = 0; kc < 4; kc++)
        s0 = __builtin_amdgcn_mfma_f32_32x32x16_f16(kf[kc], qf[kc], s0, 0, 0, 0);
    #pragma unroll
    for (int kc = 4; kc < 8; kc++)
        s1 = __builtin_amdgcn_mfma_f32_32x32x16_f16(kf[kc], qf[kc], s1, 0, 0, 0);
    float sA[16];
    #pragma unroll
    for (int r = 0; r < 16; r++) sA[r] = s0[r] + s1[r];
    // ---- S_B = K_B . Q^T (kf regs reused) ----
    #pragma unroll
    for (int kc = 0; kc < 8; kc++)
        kf[kc] = *(const half8v*)(lds + 8192 + kc * 512 + lane * 8);
    #pragma unroll
    for (int r = 0; r < 16; r++) { s0[r] = 0.0f; s1[r] = 0.0f; }
    #pragma unroll
    for (int kc = 0; kc < 4; kc++)
        s0 = __builtin_amdgcn_mfma_f32_32x32x16_f16(kf[kc], qf[kc], s0, 0, 0, 0);
    #pragma unroll
    for (int kc = 4; kc < 8; kc++)
        s1 = __builtin_amdgcn_mfma_f32_32x32x16_f16(kf[kc], qf[kc], s1, 0, 0, 0);
    float sB[16];
    #pragma unroll
    for (int r = 0; r < 16; r++) sB[r] = s0[r] + s1[r];
    // ---- softmax over 64 keys: max tree + cross-half shfl ----
    float tm[8];
    #pragma unroll
    for (int r = 0; r < 8; r++)
        tm[r] = fmaxf(fmaxf(sA[r], sA[r + 8]), fmaxf(sB[r], sB[r + 8]));
    #pragma unroll
    for (int w = 4; w; w >>= 1)
        #pragma unroll
        for (int r = 0; r < w; r++) tm[r] = fmaxf(tm[r], tm[r + w]);
    float cmax = fmaxf(tm[0], __shfl_xor(tm[0], 32, 64));
    // lazy rescale: only when max grew by >12 (p stays <= 2^12, f16-safe)
    if (__any(cmax > runm + 12.0f)) {
        const float mnew = fmaxf(runm, cmax);
        const float alpha = __builtin_amdgcn_exp2f(runm - mnew);
        #pragma unroll
        for (int dt = 0; dt < 4; dt++)
            #pragma unroll
            for (int r = 0; r < 16; r++) oacc[dt][r] *= alpha;
        lsum *= alpha;
        runm = mnew;
    }
    float pA[16], pB[16];
    #pragma unroll
    for (int r = 0; r < 16; r++) pA[r] = __builtin_amdgcn_exp2f(sA[r] - runm);
    #pragma unroll
    for (int r = 0; r < 16; r++) pB[r] = __builtin_amdgcn_exp2f(sB[r] - runm);
    float ts[8];
    #pragma unroll
    for (int r = 0; r < 8; r++) ts[r] = (pA[r] + pA[r + 8]) + (pB[r] + pB[r + 8]);
    #pragma unroll
    for (int w = 4; w; w >>= 1)
        #pragma unroll
        for (int r = 0; r < w; r++) ts[r] += ts[r + w];
    lsum += ts[0];
    uint32 hA[8], hB[8];
    #pragma unroll
    for (int t2 = 0; t2 < 8; t2++) {
        auto ka = __builtin_amdgcn_cvt_pkrtz(pA[2 * t2], pA[2 * t2 + 1]);
        hA[t2] = __builtin_bit_cast(uint32, ka);
        auto kb = __builtin_amdgcn_cvt_pkrtz(pB[2 * t2], pB[2 * t2 + 1]);
        hB[t2] = __builtin_bit_cast(uint32, kb);
    }
    // ---- PV: in-phase, V from same buffer (kf regs reused as V fragments) ----
    #pragma unroll
    for (int j = 0; j < 8; j++)
        kf[j] = *(const half8v*)(lds + (8 + j) * 512 + lane * 8);
    do_pv(kf, hA, oacc, q5);
    #pragma unroll
    for (int j = 0; j < 8; j++)
        kf[j] = *(const half8v*)(lds + 8192 + (8 + j) * 512 + lane * 8);
    do_pv(kf, hB, oacc, q5);
}

// ---------------------------------------------------------------------------
// Main flash kernel + FUSED last-arriver merge. R15 main loop (best measured:
// 53.7us, BN=64 in-phase PV, 2x32KB dbuf, (256,2), grid (S=8,64), f16
// row-major Opart). Merge fusion: the S split-blocks of each y-group bump
// counters[y] (R6-validated atomic+threadfence protocol, no spinning); the
// LAST block merges its 128 rows via fully-coalesced half8v streams -- the
// row-major f16 layout kills R6's serial-scalar tail (was 512 scalar
// loads/thread; now 64 vector loads, L2/L3-warm). Saves one graph dispatch
// (~11us by the R6/R11-vs-R8/R15 floor decomposition) + merge kernel time.
// ---------------------------------------------------------------------------
__launch_bounds__(256, 2)
__global__ void fa_main(const float* __restrict__ Qp, const _Float16* __restrict__ K16s,
                        const _Float16* __restrict__ Vs, _Float16* __restrict__ Opart,
                        float* __restrict__ lpart, float* __restrict__ mpart,
                        int* __restrict__ counters, float* __restrict__ Out, int tiles) {
    __shared__ _Float16 ldsbuf[2][16384];  // 2 x 32KB: [K_A|V_A|K_B|V_B]
    __shared__ int flag_s;
    const int tid  = threadIdx.x;
    const int lane = tid & 63;
    const int wv   = tid >> 6;
    const int l31  = lane & 31;
    const int q5   = lane >> 5;
    const int sp   = blockIdx.x;           // split id (XCD = sp at S=8)
    const int m0   = blockIdx.y * 128 + wv * 32;
    const float LOG2E = 1.44269504088896f;

    half8v qf[8];
    {
        const float* qrow = Qp + (size_t)(m0 + l31) * HDIM;
        #pragma unroll
        for (int kc = 0; kc < 8; kc++) {
            const float4 a = *(const float4*)(qrow + kc * 16 + q5 * 8);
            const float4 b = *(const float4*)(qrow + kc * 16 + q5 * 8 + 4);
            half8v h;
            h[0] = (_Float16)(a.x * LOG2E); h[1] = (_Float16)(a.y * LOG2E);
            h[2] = (_Float16)(a.z * LOG2E); h[3] = (_Float16)(a.w * LOG2E);
            h[4] = (_Float16)(b.x * LOG2E); h[5] = (_Float16)(b.y * LOG2E);
            h[6] = (_Float16)(b.z * LOG2E); h[7] = (_Float16)(b.w * LOG2E);
            qf[kc] = h;
        }
    }

    floatx16 oacc[4];
    #pragma unroll
    for (int dt = 0; dt < 4; dt++)
        #pragma unroll
        for (int r = 0; r < 16; r++) oacc[dt][r] = 0.0f;

    float runm = -3.0e38f;
    float lsum = 0.0f;

    const size_t nt0 = (size_t)sp * tiles;
    const int phases = tiles >> 1;         // 64 keys per phase

    // prologue: stage phase 0 (tiles nt0, nt0+1) into buf0
    stage_tile(K16s, Vs, ldsbuf[0], nt0 + 0, wv, lane);
    stage_tile(K16s, Vs, ldsbuf[0] + 8192, nt0 + 1, wv, lane);
    __syncthreads();
    for (int ph = 0; ph < phases; ph++) {
        _Float16* cur = ldsbuf[ph & 1];
        _Float16* nxt = ldsbuf[(ph & 1) ^ 1];
        if (ph + 1 < phases) {
            stage_tile(K16s, Vs, nxt, nt0 + 2 * ph + 2, wv, lane);
            stage_tile(K16s, Vs, nxt + 8192, nt0 + 2 * ph + 3, wv, lane);
        }
        step64(qf, oacc, runm, lsum, cur, lane, q5);
        __syncthreads();                   // publishes nxt staging; cur reusable
    }

    // ---- per-row (l, m) ----
    float ltot = lsum + __shfl_xor(lsum, 32, 64);
    if (lane < 32) {
        lpart[(size_t)sp * N_SEQ + m0 + l31] = ltot;
        mpart[(size_t)sp * N_SEQ + m0 + l31] = runm;
    }

    // ---- epilogue: LDS quarter-transpose -> row-major F16 Opart[sp][m][d] ----
    float* ldsf = (float*)ldsbuf;          // 32 rows x 132 pitch = 16.5KB
    const size_t obase = ((size_t)sp * N_SEQ + blockIdx.y * 128) * HDIM;
    #pragma unroll
    for (int qtr = 0; qtr < 4; qtr++) {
        __syncthreads();
        if (wv == qtr) {
            #pragma unroll
            for (int dt = 0; dt < 4; dt++)
                #pragma unroll
                for (int g = 0; g < 4; g++) {
                    float4 v = make_float4(oacc[dt][4 * g + 0], oacc[dt][4 * g + 1],
                                           oacc[dt][4 * g + 2], oacc[dt][4 * g + 3]);
                    *(float4*)&ldsf[l31 * 132 + dt * 32 + g * 8 + q5 * 4] = v;
                }
        }
        __syncthreads();
        const int lrow = wv * 8 + (lane >> 3);
        const int c    = lane & 7;
        const float* row = &ldsf[lrow * 132 + c * 16];
        uint32 w0[4];
        #pragma unroll
        for (int j = 0; j < 4; j++) {
            auto pk = __builtin_amdgcn_cvt_pkrtz(row[2 * j], row[2 * j + 1]);
            w0[j] = __builtin_bit_cast(uint32, pk);
        }
        uint32 w1[4];
        #pragma unroll
        for (int j = 0; j < 4; j++) {
            auto pk = __builtin_amdgcn_cvt_pkrtz(row[8 + 2 * j], row[8 + 2 * j + 1]);
            w1[j] = __builtin_bit_cast(uint32, pk);
        }
        _Float16* dst = Opart + obase + (size_t)(qtr * 32 + lrow) * HDIM + c * 16;
        *(half8v*)(dst)     = __builtin_bit_cast(half8v, make_uint4(w0[0], w0[1], w0[2], w0[3]));
        *(half8v*)(dst + 8) = __builtin_bit_cast(half8v, make_uint4(w1[0], w1[1], w1[2], w1[3]));
    }

    // ---- fused merge: last split-block of this y-group does it ----
    __syncthreads();                       // all Opart/lpart/mpart stores drained
    if (tid == 0) {
        __threadfence();                   // release our slice device-wide
        int old = atomicAdd(&counters[blockIdx.y], 1);
        flag_s = (old == (int)gridDim.x - 1);
    }
    __syncthreads();
    if (!flag_s) return;
    __threadfence();                       // acquire other splits' stores

    const int S   = gridDim.x;
    const int ym0 = blockIdx.y * 128;
    const int m   = ym0 + (tid >> 1);
    float mv[8], lv[8];
    #pragma unroll
    for (int s = 0; s < 8; s++)
        if (s < S) { mv[s] = mpart[(size_t)s * N_SEQ + m]; lv[s] = lpart[(size_t)s * N_SEQ + m]; }
    float M = -3.0e38f;
    #pragma unroll
    for (int s = 0; s < 8; s++) if (s < S) M = fmaxf(M, mv[s]);
    float wsc[8];
    float L = 0.0f;
    #pragma unroll
    for (int s = 0; s < 8; s++)
        if (s < S) { wsc[s] = __builtin_amdgcn_exp2f(mv[s] - M); L += lv[s] * wsc[s]; }
    const float inv = 1.0f / L;
    #pragma unroll
    for (int u = 0; u < 2; u++) {
        const int d0 = (tid & 1) * 64 + u * 32;
        float acc[32];
        #pragma unroll
        for (int j = 0; j < 32; j++) acc[j] = 0.0f;
        #pragma unroll
        for (int s = 0; s < 8; s++)
            if (s < S) {
                const float ww = wsc[s] * inv;
                const _Float16* src = Opart + ((size_t)s * N_SEQ + m) * HDIM + d0;
                half8v h0 = *(const half8v*)(src);
                half8v h1 = *(const half8v*)(src + 8);
                half8v h2 = *(const half8v*)(src + 16);
                half8v h3 = *(const half8v*)(src + 24);
                #pragma unroll
                for (int j = 0; j < 8; j++) {
                    acc[j]      += (float)h0[j] * ww;
                    acc[8 + j]  += (float)h1[j] * ww;
                    acc[16 + j] += (float)h2[j] * ww;
                    acc[24 + j] += (float)h3[j] * ww;
                }
            }
        float* dst = Out + (size_t)m * HDIM + d0;
        #pragma unroll
        for (int j = 0; j < 8; j++) {
            float4 v = make_float4(acc[4 * j], acc[4 * j + 1], acc[4 * j + 2], acc[4 * j + 3]);
            *(float4*)(dst + 4 * j) = v;
        }
    }
}

// ---------------------------------------------------------------------------
// Safety-net: naive fp32 flash attention (only if ws too small).
// ---------------------------------------------------------------------------
__global__ void fa_naive(const float* __restrict__ Q, const float* __restrict__ K,
                         const float* __restrict__ V, float* __restrict__ O) {
    const int m = blockIdx.x;
    const int t = threadIdx.x;
    __shared__ float qs[HDIM];
    __shared__ float ps[256];
    __shared__ float red[256];
    if (t < HDIM) qs[t] = Q[(size_t)m * HDIM + t] * 1.44269504f;
    __syncthreads();
    float om = -3.0e38f, ls = 0.0f, oa = 0.0f;
    for (int nb = 0; nb < N_SEQ; nb += 256) {
        const float* kr = K + (size_t)(nb + t) * HDIM;
        float s = 0.0f;
        #pragma unroll 8
        for (int d = 0; d < HDIM; d++) s += qs[d] * kr[d];
        red[t] = s; __syncthreads();
        for (int st = 128; st > 0; st >>= 1) { if (t < st) red[t] = fmaxf(red[t], red[t + st]); __syncthreads(); }
        float cm = red[0];
        __syncthreads();
        float mn = fmaxf(om, cm);
        float al = __builtin_amdgcn_exp2f(om - mn);
        om = mn;
        float pp = __builtin_amdgcn_exp2f(s - mn);
        ps[t] = pp; red[t] = pp; __syncthreads();
        for (int st = 128; st > 0; st >>= 1) { if (t < st) red[t] += red[t + st]; __syncthreads(); }
        float csum = red[0];
        ls = ls * al + csum;
        if (t < HDIM) {
            float acc = 0.0f;
            for (int j = 0; j < 256; j++) acc += ps[j] * V[(size_t)(nb + j) * HDIM + t];
            oa = oa * al + acc;
        }
        __syncthreads();
    }
    if (t < HDIM) O[(size_t)m * HDIM + t] = oa / ls;
}

// ---------------------------------------------------------------------------
extern "C" void kernel_launch(void* const* d_in, const int* in_sizes, int n_in,
                              void* d_out, int out_size, void* d_ws, size_t ws_size,
                              hipStream_t stream) {
    const float* q = (const float*)d_in[0];
    const float* k = (const float*)d_in[1];
    const float* v = (const float*)d_in[2];
    float* out = (float*)d_out;

    const size_t MB = 1024ull * 1024ull;
    int S = 0;
    for (int s = 8; s >= 1; s >>= 1) {               // S=8: best-measured config
        size_t need = 4 * MB + (size_t)s * (2 * MB + 64 * 1024) + 4096;
        if (ws_size >= need) { S = s; break; }
    }
    if (S == 0) {
        fa_naive<<<N_SEQ, 256, 0, stream>>>(q, k, v, out);
        return;
    }
    char* ws = (char*)d_ws;
    _Float16* K16s = (_Float16*)ws;
    _Float16* Vs   = (_Float16*)(ws + 2 * MB);
    _Float16* Opart = (_Float16*)(ws + 4 * MB);      // f16: S x 2MB
    float* lpart   = (float*)(ws + 4 * MB + (size_t)S * 2 * MB);
    float* mpart   = lpart + (size_t)S * N_SEQ;
    int*   counters = (int*)(mpart + (size_t)S * N_SEQ);  // 64 y-group counters

    prep_kv<<<dim3(N_SEQ / 32), dim3(256), 0, stream>>>(k, v, K16s, Vs, counters);
    fa_main<<<dim3(S, N_SEQ / 128), dim3(256), 0, stream>>>(
        q, K16s, Vs, Opart, lpart, mpart, counters, out, (N_SEQ / 32) / S);
}

// Round 17
// 143.475 us; speedup vs baseline: 1.1769x; 1.1769x over previous
//
#include <hip/hip_runtime.h>

#define N_SEQ 8192
#define HDIM  128

typedef _Float16 half8v  __attribute__((ext_vector_type(8)));
typedef float    floatx16 __attribute__((ext_vector_type(16)));
typedef unsigned int uint32;

// ---------------------------------------------------------------------------
// prep_kv: one block per 32-key tile. Stages K and V fp32 tiles in LDS, then
// writes f16 fragments in EXACT mfma operand order, lane-major. Also zeroes
// the 64 per-y-group merge counters (block 0) -- stream order guarantees
// this lands before fa_main's atomics, replacing a memset dispatch.
// ---------------------------------------------------------------------------
__global__ void prep_kv(const float* __restrict__ K, const float* __restrict__ V,
                        _Float16* __restrict__ K16s, _Float16* __restrict__ Vs,
                        int* __restrict__ counters) {
    __shared__ float Kl[32 * 132];
    __shared__ float Vl[32 * 132];
    const int t  = threadIdx.x;
    const int nt = blockIdx.x;
    const int n0 = nt * 32;
    if (nt == 0 && t < 64) counters[t] = 0;
    #pragma unroll
    for (int kk = 0; kk < 4; kk++) {
        int idx = t + 256 * kk;
        int nl = idx >> 5, c4 = idx & 31;
        float4 f = *(((const float4*)(K + (size_t)(n0 + nl) * HDIM)) + c4);
        float* dk = &Kl[nl * 132 + c4 * 4];
        dk[0] = f.x; dk[1] = f.y; dk[2] = f.z; dk[3] = f.w;
        float4 g = *(((const float4*)(V + (size_t)(n0 + nl) * HDIM)) + c4);
        float* dv = &Vl[nl * 132 + c4 * 4];
        dv[0] = g.x; dv[1] = g.y; dv[2] = g.z; dv[3] = g.w;
    }
    __syncthreads();
    #pragma unroll
    for (int rep = 0; rep < 2; rep++) {
        int ch = t + rep * 256;
        int kc = ch >> 6, lane = ch & 63, l31 = lane & 31, q5 = (lane >> 5) & 1;
        half8v h;
        #pragma unroll
        for (int j = 0; j < 8; j++) h[j] = (_Float16)Kl[l31 * 132 + kc * 16 + q5 * 8 + j];
        *(half8v*)(K16s + (((size_t)nt * 8 + kc) * 64 + lane) * 8) = h;
    }
    #pragma unroll
    for (int rep = 0; rep < 2; rep++) {
        int ch = t + rep * 256;
        int dt = ch >> 7, kc2 = (ch >> 6) & 1, lane = ch & 63, l31 = lane & 31, q5 = (lane >> 5) & 1;
        half8v h;
        #pragma unroll
        for (int j = 0; j < 8; j++) h[j] = (_Float16)Vl[(kc2 * 16 + q5 * 8 + j) * 132 + dt * 32 + l31];
        *(half8v*)(Vs + ((((size_t)nt * 4 + dt) * 2 + kc2) * 64 + lane) * 8) = h;
    }
}

// ---------------------------------------------------------------------------
// stage_tile: async global->LDS copy of one 32-key tile (K 8KB + V 8KB) into
// a 16KB LDS region, 4 chunks/wave. Layouts are lane-major 1KB chunks, so the
// wave-uniform-base + lane*16 LDS write pattern of global_load_lds matches.
// Completion fenced by the caller's __syncthreads (vmcnt(0) before s_barrier).
// ---------------------------------------------------------------------------
static __device__ __forceinline__ void stage_tile(
        const _Float16* __restrict__ K16s, const _Float16* __restrict__ Vs,
        _Float16* lds, size_t nt, int wv, int lane) {
    #pragma unroll
    for (int i = 0; i < 4; i++) {
        const int c = wv * 4 + i;
        const _Float16* base = (c < 8) ? (K16s + (nt * 8 + c) * 512)
                                       : (Vs + (nt * 8 + (size_t)(c - 8)) * 512);
        __builtin_amdgcn_global_load_lds(
            (const __attribute__((address_space(1))) void*)(base + lane * 8),
            (__attribute__((address_space(3))) void*)(lds + c * 512),
            16, 0, 0);
    }
}

// ---- PV: oacc += V(tile) . P(tile), P given as packed-f16 C-layout regs ----
static __device__ __forceinline__ void do_pv(const half8v (&vsrc)[8], const uint32 (&hpk)[8],
                                             floatx16 (&oacc)[4], int q5) {
    #pragma unroll
    for (int kc2 = 0; kc2 < 2; kc2++) {
        uint32 pass0 = q5 ? hpk[4 * kc2 + 0] : hpk[4 * kc2 + 2];
        uint32 pass1 = q5 ? hpk[4 * kc2 + 1] : hpk[4 * kc2 + 3];
        uint32 r0 = (uint32)__shfl_xor((int)pass0, 32, 64);
        uint32 r1 = (uint32)__shfl_xor((int)pass1, 32, 64);
        uint32 b0 = q5 ? r0 : hpk[4 * kc2 + 0];
        uint32 b1 = q5 ? r1 : hpk[4 * kc2 + 1];
        uint32 b2 = q5 ? hpk[4 * kc2 + 2] : r0;
        uint32 b3 = q5 ? hpk[4 * kc2 + 3] : r1;
        uint4 bu = make_uint4(b0, b1, b2, b3);
        half8v bfrag = __builtin_bit_cast(half8v, bu);
        #pragma unroll
        for (int dt = 0; dt < 4; dt++)
            oacc[dt] = __builtin_amdgcn_mfma_f32_32x32x16_f16(vsrc[dt * 2 + kc2], bfrag, oacc[dt], 0, 0, 0);
    }
}

// ---------------------------------------------------------------------------
// step64: one BN=64 phase (two 32-key sub-tiles A,B from one 32KB buffer).
// In-phase PV: V is ds_read AFTER softmax from the SAME buffer (stage writes
// go to the other buffer -> no cross-phase V registers, no race).
// Buffer layout: [K_A 8K][V_A 8K][K_B 8K][V_B 8K].
// ---------------------------------------------------------------------------
static __device__ __forceinline__ void step64(
        const half8v (&qf)[8], floatx16 (&oacc)[4],
        float& runm, float& lsum,
        const _Float16* lds, int lane, int q5) {
    // ---- S_A = K_A . Q^T ----
    half8v kf[8];
    #pragma unroll
    for (int kc = 0; kc < 8; kc++)
        kf[kc] = *(const half8v*)(lds + kc * 512 + lane * 8);
    floatx16 s0, s1;
    #pragma unroll
    for (int r = 0; r < 16; r++) { s0[r] = 0.0f; s1[r] = 0.0f; }
    #pragma unroll
    for (int kc = 0; kc < 4; kc++)
        s0 = __builtin_amdgcn_mfma_f32_32x32x16_f16(kf[kc], qf[kc], s0, 0, 0, 0);
    #pragma unroll
    for (int kc = 4; kc < 8; kc++)
        s1 = __builtin_amdgcn_mfma_f32_32x32x16_f16(kf[kc], qf[kc], s1, 0, 0, 0);
    float sA[16];
    #pragma unroll
    for (int r = 0; r < 16; r++) sA[r] = s0[r] + s1[r];
    // ---- S_B = K_B . Q^T (kf regs reused) ----
    #pragma unroll
    for (int kc = 0; kc < 8; kc++)
        kf[kc] = *(const half8v*)(lds + 8192 + kc * 512 + lane * 8);
    #pragma unroll
    for (int r = 0; r < 16; r++) { s0[r] = 0.0f; s1[r] = 0.0f; }
    #pragma unroll
    for (int kc = 0; kc < 4; kc++)
        s0 = __builtin_amdgcn_mfma_f32_32x32x16_f16(kf[kc], qf[kc], s0, 0, 0, 0);
    #pragma unroll
    for (int kc = 4; kc < 8; kc++)
        s1 = __builtin_amdgcn_mfma_f32_32x32x16_f16(kf[kc], qf[kc], s1, 0, 0, 0);
    float sB[16];
    #pragma unroll
    for (int r = 0; r < 16; r++) sB[r] = s0[r] + s1[r];
    // ---- softmax over 64 keys: max tree + cross-half shfl ----
    float tm[8];
    #pragma unroll
    for (int r = 0; r < 8; r++)
        tm[r] = fmaxf(fmaxf(sA[r], sA[r + 8]), fmaxf(sB[r], sB[r + 8]));
    #pragma unroll
    for (int w = 4; w; w >>= 1)
        #pragma unroll
        for (int r = 0; r < w; r++) tm[r] = fmaxf(tm[r], tm[r + w]);
    float cmax = fmaxf(tm[0], __shfl_xor(tm[0], 32, 64));
    // lazy rescale: only when max grew by >12 (p stays <= 2^12, f16-safe)
    if (__any(cmax > runm + 12.0f)) {
        const float mnew = fmaxf(runm, cmax);
        const float alpha = __builtin_amdgcn_exp2f(runm - mnew);
        #pragma unroll
        for (int dt = 0; dt < 4; dt++)
            #pragma unroll
            for (int r = 0; r < 16; r++) oacc[dt][r] *= alpha;
        lsum *= alpha;
        runm = mnew;
    }
    float pA[16], pB[16];
    #pragma unroll
    for (int r = 0; r < 16; r++) pA[r] = __builtin_amdgcn_exp2f(sA[r] - runm);
    #pragma unroll
    for (int r = 0; r < 16; r++) pB[r] = __builtin_amdgcn_exp2f(sB[r] - runm);
    float ts[8];
    #pragma unroll
    for (int r = 0; r < 8; r++) ts[r] = (pA[r] + pA[r + 8]) + (pB[r] + pB[r + 8]);
    #pragma unroll
    for (int w = 4; w; w >>= 1)
        #pragma unroll
        for (int r = 0; r < w; r++) ts[r] += ts[r + w];
    lsum += ts[0];
    uint32 hA[8], hB[8];
    #pragma unroll
    for (int t2 = 0; t2 < 8; t2++) {
        auto ka = __builtin_amdgcn_cvt_pkrtz(pA[2 * t2], pA[2 * t2 + 1]);
        hA[t2] = __builtin_bit_cast(uint32, ka);
        auto kb = __builtin_amdgcn_cvt_pkrtz(pB[2 * t2], pB[2 * t2 + 1]);
        hB[t2] = __builtin_bit_cast(uint32, kb);
    }
    // ---- PV: in-phase, V from same buffer (kf regs reused as V fragments) ----
    #pragma unroll
    for (int j = 0; j < 8; j++)
        kf[j] = *(const half8v*)(lds + (8 + j) * 512 + lane * 8);
    do_pv(kf, hA, oacc, q5);
    #pragma unroll
    for (int j = 0; j < 8; j++)
        kf[j] = *(const half8v*)(lds + 8192 + (8 + j) * 512 + lane * 8);
    do_pv(kf, hB, oacc, q5);
}

// ---------------------------------------------------------------------------
// Main flash kernel + fused SAME-XCD last-arriver merge.
// Grid (64, S): linear block id = yg + 64*sp -> XCD = yg % 8, so ALL S
// splits of a y-group run on ONE XCD. R16's fused merge (grid (S,64)) put
// each y-group's splits on 8 different XCDs; its 90us tail was the mergers
// pulling 16MB of dirty lines through cross-die coherence (per-XCD L2s are
// writeback + non-coherent; the fence protocol is correct but resolves
// line-by-line). Same-XCD: writer L2 == reader L2 -> merge tail is local-L2
// half8v streams. Trade: each XCD's L2 now holds all splits' K/V (4MB).
// Main loop = R15's best-measured (53.7us): BN=64 in-phase PV, 2x32KB dbuf,
// (256,2), f16 row-major Opart.
// ---------------------------------------------------------------------------
__launch_bounds__(256, 2)
__global__ void fa_main(const float* __restrict__ Qp, const _Float16* __restrict__ K16s,
                        const _Float16* __restrict__ Vs, _Float16* __restrict__ Opart,
                        float* __restrict__ lpart, float* __restrict__ mpart,
                        int* __restrict__ counters, float* __restrict__ Out, int tiles) {
    __shared__ _Float16 ldsbuf[2][16384];  // 2 x 32KB: [K_A|V_A|K_B|V_B]
    __shared__ int flag_s;
    const int tid  = threadIdx.x;
    const int lane = tid & 63;
    const int wv   = tid >> 6;
    const int l31  = lane & 31;
    const int q5   = lane >> 5;
    const int yg   = blockIdx.x;           // y-group (XCD = yg % 8)
    const int sp   = blockIdx.y;           // split id (same XCD for all sp)
    const int m0   = yg * 128 + wv * 32;
    const float LOG2E = 1.44269504088896f;

    half8v qf[8];
    {
        const float* qrow = Qp + (size_t)(m0 + l31) * HDIM;
        #pragma unroll
        for (int kc = 0; kc < 8; kc++) {
            const float4 a = *(const float4*)(qrow + kc * 16 + q5 * 8);
            const float4 b = *(const float4*)(qrow + kc * 16 + q5 * 8 + 4);
            half8v h;
            h[0] = (_Float16)(a.x * LOG2E); h[1] = (_Float16)(a.y * LOG2E);
            h[2] = (_Float16)(a.z * LOG2E); h[3] = (_Float16)(a.w * LOG2E);
            h[4] = (_Float16)(b.x * LOG2E); h[5] = (_Float16)(b.y * LOG2E);
            h[6] = (_Float16)(b.z * LOG2E); h[7] = (_Float16)(b.w * LOG2E);
            qf[kc] = h;
        }
    }

    floatx16 oacc[4];
    #pragma unroll
    for (int dt = 0; dt < 4; dt++)
        #pragma unroll
        for (int r = 0; r < 16; r++) oacc[dt][r] = 0.0f;

    float runm = -3.0e38f;
    float lsum = 0.0f;

    const size_t nt0 = (size_t)sp * tiles;
    const int phases = tiles >> 1;         // 64 keys per phase

    // prologue: stage phase 0 (tiles nt0, nt0+1) into buf0
    stage_tile(K16s, Vs, ldsbuf[0], nt0 + 0, wv, lane);
    stage_tile(K16s, Vs, ldsbuf[0] + 8192, nt0 + 1, wv, lane);
    __syncthreads();
    for (int ph = 0; ph < phases; ph++) {
        _Float16* cur = ldsbuf[ph & 1];
        _Float16* nxt = ldsbuf[(ph & 1) ^ 1];
        if (ph + 1 < phases) {
            stage_tile(K16s, Vs, nxt, nt0 + 2 * ph + 2, wv, lane);
            stage_tile(K16s, Vs, nxt + 8192, nt0 + 2 * ph + 3, wv, lane);
        }
        step64(qf, oacc, runm, lsum, cur, lane, q5);
        __syncthreads();                   // publishes nxt staging; cur reusable
    }

    // ---- per-row (l, m) ----
    float ltot = lsum + __shfl_xor(lsum, 32, 64);
    if (lane < 32) {
        lpart[(size_t)sp * N_SEQ + m0 + l31] = ltot;
        mpart[(size_t)sp * N_SEQ + m0 + l31] = runm;
    }

    // ---- epilogue: LDS quarter-transpose -> row-major F16 Opart[sp][m][d] ----
    float* ldsf = (float*)ldsbuf;          // 32 rows x 132 pitch = 16.5KB
    const size_t obase = ((size_t)sp * N_SEQ + (size_t)yg * 128) * HDIM;
    #pragma unroll
    for (int qtr = 0; qtr < 4; qtr++) {
        __syncthreads();
        if (wv == qtr) {
            #pragma unroll
            for (int dt = 0; dt < 4; dt++)
                #pragma unroll
                for (int g = 0; g < 4; g++) {
                    float4 v = make_float4(oacc[dt][4 * g + 0], oacc[dt][4 * g + 1],
                                           oacc[dt][4 * g + 2], oacc[dt][4 * g + 3]);
                    *(float4*)&ldsf[l31 * 132 + dt * 32 + g * 8 + q5 * 4] = v;
                }
        }
        __syncthreads();
        const int lrow = wv * 8 + (lane >> 3);
        const int c    = lane & 7;
        const float* row = &ldsf[lrow * 132 + c * 16];
        uint32 w0[4];
        #pragma unroll
        for (int j = 0; j < 4; j++) {
            auto pk = __builtin_amdgcn_cvt_pkrtz(row[2 * j], row[2 * j + 1]);
            w0[j] = __builtin_bit_cast(uint32, pk);
        }
        uint32 w1[4];
        #pragma unroll
        for (int j = 0; j < 4; j++) {
            auto pk = __builtin_amdgcn_cvt_pkrtz(row[8 + 2 * j], row[8 + 2 * j + 1]);
            w1[j] = __builtin_bit_cast(uint32, pk);
        }
        _Float16* dst = Opart + obase + (size_t)(qtr * 32 + lrow) * HDIM + c * 16;
        *(half8v*)(dst)     = __builtin_bit_cast(half8v, make_uint4(w0[0], w0[1], w0[2], w0[3]));
        *(half8v*)(dst + 8) = __builtin_bit_cast(half8v, make_uint4(w1[0], w1[1], w1[2], w1[3]));
    }

    // ---- fused merge: last split-block of this y-group (SAME XCD) ----
    __syncthreads();                       // all Opart/lpart/mpart stores drained
    if (tid == 0) {
        __threadfence();                   // release our slice
        int old = atomicAdd(&counters[yg], 1);
        flag_s = (old == (int)gridDim.y - 1);
    }
    __syncthreads();
    if (!flag_s) return;
    __threadfence();                       // acquire other splits' stores (local L2)

    const int S   = gridDim.y;
    const int ym0 = yg * 128;
    const int m   = ym0 + (tid >> 1);
    float mv[8], lv[8];
    #pragma unroll
    for (int s = 0; s < 8; s++)
        if (s < S) { mv[s] = mpart[(size_t)s * N_SEQ + m]; lv[s] = lpart[(size_t)s * N_SEQ + m]; }
    float M = -3.0e38f;
    #pragma unroll
    for (int s = 0; s < 8; s++) if (s < S) M = fmaxf(M, mv[s]);
    float wsc[8];
    float L = 0.0f;
    #pragma unroll
    for (int s = 0; s < 8; s++)
        if (s < S) { wsc[s] = __builtin_amdgcn_exp2f(mv[s] - M); L += lv[s] * wsc[s]; }
    const float inv = 1.0f / L;
    #pragma unroll
    for (int u = 0; u < 2; u++) {
        const int d0 = (tid & 1) * 64 + u * 32;
        float acc[32];
        #pragma unroll
        for (int j = 0; j < 32; j++) acc[j] = 0.0f;
        #pragma unroll
        for (int s = 0; s < 8; s++)
            if (s < S) {
                const float ww = wsc[s] * inv;
                const _Float16* src = Opart + ((size_t)s * N_SEQ + m) * HDIM + d0;
                half8v h0 = *(const half8v*)(src);
                half8v h1 = *(const half8v*)(src + 8);
                half8v h2 = *(const half8v*)(src + 16);
                half8v h3 = *(const half8v*)(src + 24);
                #pragma unroll
                for (int j = 0; j < 8; j++) {
                    acc[j]      += (float)h0[j] * ww;
                    acc[8 + j]  += (float)h1[j] * ww;
                    acc[16 + j] += (float)h2[j] * ww;
                    acc[24 + j] += (float)h3[j] * ww;
                }
            }
        float* dst = Out + (size_t)m * HDIM + d0;
        #pragma unroll
        for (int j = 0; j < 8; j++) {
            float4 v = make_float4(acc[4 * j], acc[4 * j + 1], acc[4 * j + 2], acc[4 * j + 3]);
            *(float4*)(dst + 4 * j) = v;
        }
    }
}

// ---------------------------------------------------------------------------
// Safety-net: naive fp32 flash attention (only if ws too small).
// ---------------------------------------------------------------------------
__global__ void fa_naive(const float* __restrict__ Q, const float* __restrict__ K,
                         const float* __restrict__ V, float* __restrict__ O) {
    const int m = blockIdx.x;
    const int t = threadIdx.x;
    __shared__ float qs[HDIM];
    __shared__ float ps[256];
    __shared__ float red[256];
    if (t < HDIM) qs[t] = Q[(size_t)m * HDIM + t] * 1.44269504f;
    __syncthreads();
    float om = -3.0e38f, ls = 0.0f, oa = 0.0f;
    for (int nb = 0; nb < N_SEQ; nb += 256) {
        const float* kr = K + (size_t)(nb + t) * HDIM;
        float s = 0.0f;
        #pragma unroll 8
        for (int d = 0; d < HDIM; d++) s += qs[d] * kr[d];
        red[t] = s; __syncthreads();
        for (int st = 128; st > 0; st >>= 1) { if (t < st) red[t] = fmaxf(red[t], red[t + st]); __syncthreads(); }
        float cm = red[0];
        __syncthreads();
        float mn = fmaxf(om, cm);
        float al = __builtin_amdgcn_exp2f(om - mn);
        om = mn;
        float pp = __builtin_amdgcn_exp2f(s - mn);
        ps[t] = pp; red[t] = pp; __syncthreads();
        for (int st = 128; st > 0; st >>= 1) { if (t < st) red[t] += red[t + st]; __syncthreads(); }
        float csum = red[0];
        ls = ls * al + csum;
        if (t < HDIM) {
            float acc = 0.0f;
            for (int j = 0; j < 256; j++) acc += ps[j] * V[(size_t)(nb + j) * HDIM + t];
            oa = oa * al + acc;
        }
        __syncthreads();
    }
    if (t < HDIM) O[(size_t)m * HDIM + t] = oa / ls;
}

// ---------------------------------------------------------------------------
extern "C" void kernel_launch(void* const* d_in, const int* in_sizes, int n_in,
                              void* d_out, int out_size, void* d_ws, size_t ws_size,
                              hipStream_t stream) {
    const float* q = (const float*)d_in[0];
    const float* k = (const float*)d_in[1];
    const float* v = (const float*)d_in[2];
    float* out = (float*)d_out;

    const size_t MB = 1024ull * 1024ull;
    int S = 0;
    for (int s = 8; s >= 1; s >>= 1) {               // S=8: best-measured config
        size_t need = 4 * MB + (size_t)s * (2 * MB + 64 * 1024) + 4096;
        if (ws_size >= need) { S = s; break; }
    }
    if (S == 0) {
        fa_naive<<<N_SEQ, 256, 0, stream>>>(q, k, v, out);
        return;
    }
    char* ws = (char*)d_ws;
    _Float16* K16s = (_Float16*)ws;
    _Float16* Vs   = (_Float16*)(ws + 2 * MB);
    _Float16* Opart = (_Float16*)(ws + 4 * MB);      // f16: S x 2MB
    float* lpart   = (float*)(ws + 4 * MB + (size_t)S * 2 * MB);
    float* mpart   = lpart + (size_t)S * N_SEQ;
    int*   counters = (int*)(mpart + (size_t)S * N_SEQ);  // 64 y-group counters

    prep_kv<<<dim3(N_SEQ / 32), dim3(256), 0, stream>>>(k, v, K16s, Vs, counters);
    // grid (64, S): all S splits of a y-group on the same XCD (yg % 8)
    fa_main<<<dim3(N_SEQ / 128, S), dim3(256), 0, stream>>>(
        q, K16s, Vs, Opart, lpart, mpart, counters, out, (N_SEQ / 32) / S);
}

// Round 18
// 117.958 us; speedup vs baseline: 1.4315x; 1.2163x over previous
//
#include <hip/hip_runtime.h>

#define N_SEQ 8192
#define HDIM  128

typedef _Float16 half8v  __attribute__((ext_vector_type(8)));
typedef float    floatx16 __attribute__((ext_vector_type(16)));
typedef unsigned int uint32;

// ---------------------------------------------------------------------------
// prep_kv: one block per 32-key tile. Stages K and V fp32 tiles in LDS, then
// writes f16 fragments in EXACT mfma operand order, lane-major, so fa_main's
// fragment loads are fully coalesced 1KB wave loads (and 1KB-chunk LDS-stageable).
// ---------------------------------------------------------------------------
__global__ void prep_kv(const float* __restrict__ K, const float* __restrict__ V,
                        _Float16* __restrict__ K16s, _Float16* __restrict__ Vs) {
    __shared__ float Kl[32 * 132];
    __shared__ float Vl[32 * 132];
    const int t  = threadIdx.x;
    const int nt = blockIdx.x;
    const int n0 = nt * 32;
    #pragma unroll
    for (int kk = 0; kk < 4; kk++) {
        int idx = t + 256 * kk;
        int nl = idx >> 5, c4 = idx & 31;
        float4 f = *(((const float4*)(K + (size_t)(n0 + nl) * HDIM)) + c4);
        float* dk = &Kl[nl * 132 + c4 * 4];
        dk[0] = f.x; dk[1] = f.y; dk[2] = f.z; dk[3] = f.w;
        float4 g = *(((const float4*)(V + (size_t)(n0 + nl) * HDIM)) + c4);
        float* dv = &Vl[nl * 132 + c4 * 4];
        dv[0] = g.x; dv[1] = g.y; dv[2] = g.z; dv[3] = g.w;
    }
    __syncthreads();
    #pragma unroll
    for (int rep = 0; rep < 2; rep++) {
        int ch = t + rep * 256;
        int kc = ch >> 6, lane = ch & 63, l31 = lane & 31, q5 = (lane >> 5) & 1;
        half8v h;
        #pragma unroll
        for (int j = 0; j < 8; j++) h[j] = (_Float16)Kl[l31 * 132 + kc * 16 + q5 * 8 + j];
        *(half8v*)(K16s + (((size_t)nt * 8 + kc) * 64 + lane) * 8) = h;
    }
    #pragma unroll
    for (int rep = 0; rep < 2; rep++) {
        int ch = t + rep * 256;
        int dt = ch >> 7, kc2 = (ch >> 6) & 1, lane = ch & 63, l31 = lane & 31, q5 = (lane >> 5) & 1;
        half8v h;
        #pragma unroll
        for (int j = 0; j < 8; j++) h[j] = (_Float16)Vl[(kc2 * 16 + q5 * 8 + j) * 132 + dt * 32 + l31];
        *(half8v*)(Vs + ((((size_t)nt * 4 + dt) * 2 + kc2) * 64 + lane) * 8) = h;
    }
}

// ---------------------------------------------------------------------------
// stage_tile: async global->LDS copy of one 32-key tile (K 8KB + V 8KB) into
// a 16KB LDS region, 4 chunks/wave. Layouts are lane-major 1KB chunks, so the
// wave-uniform-base + lane*16 LDS write pattern of global_load_lds matches.
// Completion fenced by the caller's __syncthreads (vmcnt(0) before s_barrier).
// ---------------------------------------------------------------------------
static __device__ __forceinline__ void stage_tile(
        const _Float16* __restrict__ K16s, const _Float16* __restrict__ Vs,
        _Float16* lds, size_t nt, int wv, int lane) {
    #pragma unroll
    for (int i = 0; i < 4; i++) {
        const int c = wv * 4 + i;
        const _Float16* base = (c < 8) ? (K16s + (nt * 8 + c) * 512)
                                       : (Vs + (nt * 8 + (size_t)(c - 8)) * 512);
        __builtin_amdgcn_global_load_lds(
            (const __attribute__((address_space(1))) void*)(base + lane * 8),
            (__attribute__((address_space(3))) void*)(lds + c * 512),
            16, 0, 0);
    }
}

// ---- PV: oacc += V(tile) . P(tile), P given as packed-f16 C-layout regs ----
static __device__ __forceinline__ void do_pv(const half8v (&vsrc)[8], const uint32 (&hpk)[8],
                                             floatx16 (&oacc)[4], int q5) {
    #pragma unroll
    for (int kc2 = 0; kc2 < 2; kc2++) {
        uint32 pass0 = q5 ? hpk[4 * kc2 + 0] : hpk[4 * kc2 + 2];
        uint32 pass1 = q5 ? hpk[4 * kc2 + 1] : hpk[4 * kc2 + 3];
        uint32 r0 = (uint32)__shfl_xor((int)pass0, 32, 64);
        uint32 r1 = (uint32)__shfl_xor((int)pass1, 32, 64);
        uint32 b0 = q5 ? r0 : hpk[4 * kc2 + 0];
        uint32 b1 = q5 ? r1 : hpk[4 * kc2 + 1];
        uint32 b2 = q5 ? hpk[4 * kc2 + 2] : r0;
        uint32 b3 = q5 ? hpk[4 * kc2 + 3] : r1;
        uint4 bu = make_uint4(b0, b1, b2, b3);
        half8v bfrag = __builtin_bit_cast(half8v, bu);
        #pragma unroll
        for (int dt = 0; dt < 4; dt++)
            oacc[dt] = __builtin_amdgcn_mfma_f32_32x32x16_f16(vsrc[dt * 2 + kc2], bfrag, oacc[dt], 0, 0, 0);
    }
}

// ---------------------------------------------------------------------------
// step64: one BN=64 phase (two 32-key sub-tiles A,B from one 32KB buffer).
// In-phase PV: V is ds_read AFTER softmax from the SAME buffer (stage writes
// go to the other buffer -> no cross-phase V registers, no race).
// Buffer layout: [K_A 8K][V_A 8K][K_B 8K][V_B 8K].
// ---------------------------------------------------------------------------
static __device__ __forceinline__ void step64(
        const half8v (&qf)[8], floatx16 (&oacc)[4],
        float& runm, float& lsum,
        const _Float16* lds, int lane, int q5) {
    // ---- S_A = K_A . Q^T ----
    half8v kf[8];
    #pragma unroll
    for (int kc = 0; kc < 8; kc++)
        kf[kc] = *(const half8v*)(lds + kc * 512 + lane * 8);
    floatx16 s0, s1;
    #pragma unroll
    for (int r = 0; r < 16; r++) { s0[r] = 0.0f; s1[r] = 0.0f; }
    #pragma unroll
    for (int kc = 0; kc < 4; kc++)
        s0 = __builtin_amdgcn_mfma_f32_32x32x16_f16(kf[kc], qf[kc], s0, 0, 0, 0);
    #pragma unroll
    for (int kc = 4; kc < 8; kc++)
        s1 = __builtin_amdgcn_mfma_f32_32x32x16_f16(kf[kc], qf[kc], s1, 0, 0, 0);
    float sA[16];
    #pragma unroll
    for (int r = 0; r < 16; r++) sA[r] = s0[r] + s1[r];
    // ---- S_B = K_B . Q^T (kf regs reused) ----
    #pragma unroll
    for (int kc = 0; kc < 8; kc++)
        kf[kc] = *(const half8v*)(lds + 8192 + kc * 512 + lane * 8);
    #pragma unroll
    for (int r = 0; r < 16; r++) { s0[r] = 0.0f; s1[r] = 0.0f; }
    #pragma unroll
    for (int kc = 0; kc < 4; kc++)
        s0 = __builtin_amdgcn_mfma_f32_32x32x16_f16(kf[kc], qf[kc], s0, 0, 0, 0);
    #pragma unroll
    for (int kc = 4; kc < 8; kc++)
        s1 = __builtin_amdgcn_mfma_f32_32x32x16_f16(kf[kc], qf[kc], s1, 0, 0, 0);
    float sB[16];
    #pragma unroll
    for (int r = 0; r < 16; r++) sB[r] = s0[r] + s1[r];
    // ---- softmax over 64 keys: max tree + cross-half shfl ----
    float tm[8];
    #pragma unroll
    for (int r = 0; r < 8; r++)
        tm[r] = fmaxf(fmaxf(sA[r], sA[r + 8]), fmaxf(sB[r], sB[r + 8]));
    #pragma unroll
    for (int w = 4; w; w >>= 1)
        #pragma unroll
        for (int r = 0; r < w; r++) tm[r] = fmaxf(tm[r], tm[r + w]);
    float cmax = fmaxf(tm[0], __shfl_xor(tm[0], 32, 64));
    // lazy rescale: only when max grew by >12 (p stays <= 2^12, f16-safe)
    if (__any(cmax > runm + 12.0f)) {
        const float mnew = fmaxf(runm, cmax);
        const float alpha = __builtin_amdgcn_exp2f(runm - mnew);
        #pragma unroll
        for (int dt = 0; dt < 4; dt++)
            #pragma unroll
            for (int r = 0; r < 16; r++) oacc[dt][r] *= alpha;
        lsum *= alpha;
        runm = mnew;
    }
    float pA[16], pB[16];
    #pragma unroll
    for (int r = 0; r < 16; r++) pA[r] = __builtin_amdgcn_exp2f(sA[r] - runm);
    #pragma unroll
    for (int r = 0; r < 16; r++) pB[r] = __builtin_amdgcn_exp2f(sB[r] - runm);
    float ts[8];
    #pragma unroll
    for (int r = 0; r < 8; r++) ts[r] = (pA[r] + pA[r + 8]) + (pB[r] + pB[r + 8]);
    #pragma unroll
    for (int w = 4; w; w >>= 1)
        #pragma unroll
        for (int r = 0; r < w; r++) ts[r] += ts[r + w];
    lsum += ts[0];
    uint32 hA[8], hB[8];
    #pragma unroll
    for (int t2 = 0; t2 < 8; t2++) {
        auto ka = __builtin_amdgcn_cvt_pkrtz(pA[2 * t2], pA[2 * t2 + 1]);
        hA[t2] = __builtin_bit_cast(uint32, ka);
        auto kb = __builtin_amdgcn_cvt_pkrtz(pB[2 * t2], pB[2 * t2 + 1]);
        hB[t2] = __builtin_bit_cast(uint32, kb);
    }
    // ---- PV: in-phase, V from same buffer (kf regs reused as V fragments) ----
    #pragma unroll
    for (int j = 0; j < 8; j++)
        kf[j] = *(const half8v*)(lds + (8 + j) * 512 + lane * 8);
    do_pv(kf, hA, oacc, q5);
    #pragma unroll
    for (int j = 0; j < 8; j++)
        kf[j] = *(const half8v*)(lds + 8192 + (8 + j) * 512 + lane * 8);
    do_pv(kf, hB, oacc, q5);
}

// ---------------------------------------------------------------------------
// Main flash kernel: best-measured configuration (R15, total 118.75us).
// BN=64 in-phase pipeline, 4 waves x 32 query rows, 2x32KB LDS double buffer,
// __launch_bounds__(256,2), grid (S=8, 64) -> XCD = sp. Epilogue converts the
// transposed output tile to F16 row-major Opart[sp][m][d] (halves partial
// traffic; absmax unchanged at 0.03125).
// Session ledger: occupancy 3w/SIMD null (R14, critical-path-bound); counted
// vmcnt null (R10); phase halving +5% (R12); fused merge closed after 3
// attempts (R6/R16/R17 -- in-kernel producer-consumer handoff always loses
// to the kernel-boundary L2 flush, even same-XCD).
// ---------------------------------------------------------------------------
__launch_bounds__(256, 2)
__global__ void fa_main(const float* __restrict__ Qp, const _Float16* __restrict__ K16s,
                        const _Float16* __restrict__ Vs, _Float16* __restrict__ Opart,
                        float* __restrict__ lpart, float* __restrict__ mpart, int tiles) {
    __shared__ _Float16 ldsbuf[2][16384];  // 2 x 32KB: [K_A|V_A|K_B|V_B]
    const int tid  = threadIdx.x;
    const int lane = tid & 63;
    const int wv   = tid >> 6;
    const int l31  = lane & 31;
    const int q5   = lane >> 5;
    const int sp   = blockIdx.x;           // split id (XCD = sp at S=8)
    const int m0   = blockIdx.y * 128 + wv * 32;
    const float LOG2E = 1.44269504088896f;

    half8v qf[8];
    {
        const float* qrow = Qp + (size_t)(m0 + l31) * HDIM;
        #pragma unroll
        for (int kc = 0; kc < 8; kc++) {
            const float4 a = *(const float4*)(qrow + kc * 16 + q5 * 8);
            const float4 b = *(const float4*)(qrow + kc * 16 + q5 * 8 + 4);
            half8v h;
            h[0] = (_Float16)(a.x * LOG2E); h[1] = (_Float16)(a.y * LOG2E);
            h[2] = (_Float16)(a.z * LOG2E); h[3] = (_Float16)(a.w * LOG2E);
            h[4] = (_Float16)(b.x * LOG2E); h[5] = (_Float16)(b.y * LOG2E);
            h[6] = (_Float16)(b.z * LOG2E); h[7] = (_Float16)(b.w * LOG2E);
            qf[kc] = h;
        }
    }

    floatx16 oacc[4];
    #pragma unroll
    for (int dt = 0; dt < 4; dt++)
        #pragma unroll
        for (int r = 0; r < 16; r++) oacc[dt][r] = 0.0f;

    float runm = -3.0e38f;
    float lsum = 0.0f;

    const size_t nt0 = (size_t)sp * tiles;
    const int phases = tiles >> 1;         // 64 keys per phase

    // prologue: stage phase 0 (tiles nt0, nt0+1) into buf0
    stage_tile(K16s, Vs, ldsbuf[0], nt0 + 0, wv, lane);
    stage_tile(K16s, Vs, ldsbuf[0] + 8192, nt0 + 1, wv, lane);
    __syncthreads();
    for (int ph = 0; ph < phases; ph++) {
        _Float16* cur = ldsbuf[ph & 1];
        _Float16* nxt = ldsbuf[(ph & 1) ^ 1];
        if (ph + 1 < phases) {
            stage_tile(K16s, Vs, nxt, nt0 + 2 * ph + 2, wv, lane);
            stage_tile(K16s, Vs, nxt + 8192, nt0 + 2 * ph + 3, wv, lane);
        }
        step64(qf, oacc, runm, lsum, cur, lane, q5);
        __syncthreads();                   // publishes nxt staging; cur reusable
    }

    // ---- per-row (l, m) ----
    float ltot = lsum + __shfl_xor(lsum, 32, 64);
    if (lane < 32) {
        lpart[(size_t)sp * N_SEQ + m0 + l31] = ltot;
        mpart[(size_t)sp * N_SEQ + m0 + l31] = runm;
    }

    // ---- epilogue: LDS quarter-transpose -> row-major F16 Opart[sp][m][d] ----
    // oacc[dt][4g+e] holds column d = dt*32 + g*8 + q5*4 + e of row m0+l31.
    float* ldsf = (float*)ldsbuf;          // 32 rows x 132 pitch = 16.5KB
    const size_t obase = ((size_t)sp * N_SEQ + blockIdx.y * 128) * HDIM;
    #pragma unroll
    for (int qtr = 0; qtr < 4; qtr++) {
        __syncthreads();
        if (wv == qtr) {
            #pragma unroll
            for (int dt = 0; dt < 4; dt++)
                #pragma unroll
                for (int g = 0; g < 4; g++) {
                    float4 v = make_float4(oacc[dt][4 * g + 0], oacc[dt][4 * g + 1],
                                           oacc[dt][4 * g + 2], oacc[dt][4 * g + 3]);
                    *(float4*)&ldsf[l31 * 132 + dt * 32 + g * 8 + q5 * 4] = v;
                }
        }
        __syncthreads();
        // stream quarter out as f16: thread -> 16 f16 (rows wv*8.., 16-col chunk)
        const int lrow = wv * 8 + (lane >> 3);
        const int c    = lane & 7;
        const float* row = &ldsf[lrow * 132 + c * 16];
        uint32 w0[4];
        #pragma unroll
        for (int j = 0; j < 4; j++) {
            auto pk = __builtin_amdgcn_cvt_pkrtz(row[2 * j], row[2 * j + 1]);
            w0[j] = __builtin_bit_cast(uint32, pk);
        }
        uint32 w1[4];
        #pragma unroll
        for (int j = 0; j < 4; j++) {
            auto pk = __builtin_amdgcn_cvt_pkrtz(row[8 + 2 * j], row[8 + 2 * j + 1]);
            w1[j] = __builtin_bit_cast(uint32, pk);
        }
        _Float16* dst = Opart + obase + (size_t)(qtr * 32 + lrow) * HDIM + c * 16;
        *(half8v*)(dst)     = __builtin_bit_cast(half8v, make_uint4(w0[0], w0[1], w0[2], w0[3]));
        *(half8v*)(dst + 8) = __builtin_bit_cast(half8v, make_uint4(w1[0], w1[1], w1[2], w1[3]));
    }
}

// ---------------------------------------------------------------------------
// Merge: grid N/32 = 256 blocks x 256 threads. Opart is f16 row-major
// [s][m][d]: all loads are coalesced 16B half8v streams; accumulate fp32;
// write fp32 Out. Thread: row m = blk*32 + t/8, 16-col chunk c = t&7.
// ---------------------------------------------------------------------------
template <int S>
__global__ __launch_bounds__(256) void fa_merge(const _Float16* __restrict__ Opart,
                                                const float* __restrict__ lpart,
                                                const float* __restrict__ mpart,
                                                float* __restrict__ Out) {
    const int t = threadIdx.x;
    const int m = blockIdx.x * 32 + (t >> 3);
    const int c = t & 7;

    float mv[S], lv[S];
    #pragma unroll
    for (int s = 0; s < S; s++) {
        mv[s] = mpart[(size_t)s * N_SEQ + m];
        lv[s] = lpart[(size_t)s * N_SEQ + m];
    }
    float M = -3.0e38f;
    #pragma unroll
    for (int s = 0; s < S; s++) M = fmaxf(M, mv[s]);
    float wsc[S];
    float L = 0.0f;
    #pragma unroll
    for (int s = 0; s < S; s++) {
        wsc[s] = __builtin_amdgcn_exp2f(mv[s] - M);
        L += lv[s] * wsc[s];
    }
    const float inv = 1.0f / L;

    float acc[16];
    #pragma unroll
    for (int j = 0; j < 16; j++) acc[j] = 0.0f;
    #pragma unroll
    for (int s = 0; s < S; s++) {
        const float ww = wsc[s] * inv;
        const _Float16* src = Opart + ((size_t)s * N_SEQ + m) * HDIM + c * 16;
        half8v h0 = *(const half8v*)(src);
        half8v h1 = *(const half8v*)(src + 8);
        #pragma unroll
        for (int j = 0; j < 8; j++) acc[j]     += (float)h0[j] * ww;
        #pragma unroll
        for (int j = 0; j < 8; j++) acc[8 + j] += (float)h1[j] * ww;
    }
    float* dst = Out + (size_t)m * HDIM + c * 16;
    #pragma unroll
    for (int j = 0; j < 4; j++) {
        float4 v = make_float4(acc[4 * j], acc[4 * j + 1], acc[4 * j + 2], acc[4 * j + 3]);
        *(float4*)(dst + 4 * j) = v;
    }
}

// ---------------------------------------------------------------------------
// Safety-net: naive fp32 flash attention (only if ws too small).
// ---------------------------------------------------------------------------
__global__ void fa_naive(const float* __restrict__ Q, const float* __restrict__ K,
                         const float* __restrict__ V, float* __restrict__ O) {
    const int m = blockIdx.x;
    const int t = threadIdx.x;
    __shared__ float qs[HDIM];
    __shared__ float ps[256];
    __shared__ float red[256];
    if (t < HDIM) qs[t] = Q[(size_t)m * HDIM + t] * 1.44269504f;
    __syncthreads();
    float om = -3.0e38f, ls = 0.0f, oa = 0.0f;
    for (int nb = 0; nb < N_SEQ; nb += 256) {
        const float* kr = K + (size_t)(nb + t) * HDIM;
        float s = 0.0f;
        #pragma unroll 8
        for (int d = 0; d < HDIM; d++) s += qs[d] * kr[d];
        red[t] = s; __syncthreads();
        for (int st = 128; st > 0; st >>= 1) { if (t < st) red[t] = fmaxf(red[t], red[t + st]); __syncthreads(); }
        float cm = red[0];
        __syncthreads();
        float mn = fmaxf(om, cm);
        float al = __builtin_amdgcn_exp2f(om - mn);
        om = mn;
        float pp = __builtin_amdgcn_exp2f(s - mn);
        ps[t] = pp; red[t] = pp; __syncthreads();
        for (int st = 128; st > 0; st >>= 1) { if (t < st) red[t] += red[t + st]; __syncthreads(); }
        float csum = red[0];
        ls = ls * al + csum;
        if (t < HDIM) {
            float acc = 0.0f;
            for (int j = 0; j < 256; j++) acc += ps[j] * V[(size_t)(nb + j) * HDIM + t];
            oa = oa * al + acc;
        }
        __syncthreads();
    }
    if (t < HDIM) O[(size_t)m * HDIM + t] = oa / ls;
}

// ---------------------------------------------------------------------------
extern "C" void kernel_launch(void* const* d_in, const int* in_sizes, int n_in,
                              void* d_out, int out_size, void* d_ws, size_t ws_size,
                              hipStream_t stream) {
    const float* q = (const float*)d_in[0];
    const float* k = (const float*)d_in[1];
    const float* v = (const float*)d_in[2];
    float* out = (float*)d_out;

    const size_t MB = 1024ull * 1024ull;
    int S = 0;
    for (int s = 8; s >= 1; s >>= 1) {               // S=8: best-measured config
        size_t need = 4 * MB + (size_t)s * (2 * MB + 64 * 1024);
        if (ws_size >= need) { S = s; break; }
    }
    if (S == 0) {
        fa_naive<<<N_SEQ, 256, 0, stream>>>(q, k, v, out);
        return;
    }
    char* ws = (char*)d_ws;
    _Float16* K16s = (_Float16*)ws;
    _Float16* Vs   = (_Float16*)(ws + 2 * MB);
    _Float16* Opart = (_Float16*)(ws + 4 * MB);      // f16: S x 2MB
    float* lpart   = (float*)(ws + 4 * MB + (size_t)S * 2 * MB);
    float* mpart   = lpart + (size_t)S * N_SEQ;

    prep_kv<<<dim3(N_SEQ / 32), dim3(256), 0, stream>>>(k, v, K16s, Vs);
    fa_main<<<dim3(S, N_SEQ / 128), dim3(256), 0, stream>>>(q, K16s, Vs, Opart, lpart, mpart, (N_SEQ / 32) / S);
    dim3 mg(N_SEQ / 32);
    switch (S) {
        case 8:  fa_merge<8> <<<mg, dim3(256), 0, stream>>>(Opart, lpart, mpart, out); break;
        case 4:  fa_merge<4> <<<mg, dim3(256), 0, stream>>>(Opart, lpart, mpart, out); break;
        case 2:  fa_merge<2> <<<mg, dim3(256), 0, stream>>>(Opart, lpart, mpart, out); break;
        default: fa_merge<1> <<<mg, dim3(256), 0, stream>>>(Opart, lpart, mpart, out); break;
    }
}